// Round 16
// baseline (18069.897 us; speedup 1.0000x reference)
//
#include <hip/hip_runtime.h>
#include <cstdint>

#define B_   32
#define T_   500
#define H_   512
#define ENC_ 1024
#define V_   10000
#define L_   100
#define H4_  2048
#define NB_  256
#define NT_  1024

// workspace layout (float offsets)
#define OFF_HPROJ 0          // bf16 [16000][512]
#define OFF_WYYP  4096000    // bf16 HI-ONLY [625 vt][16 kc][64][8]
#define OFF_WRECP 6656000    // bf16 HI-ONLY [160 vt][48 kc][64][8]
#define OFF_WSB   10588160   // bf16 [512 k][512 col]
#define OFF_S     10719232   // packed (bf16hi<<16)|lo of s, 32 x 512 uints
#define OFF_DECTP 10735616   // packed (bf16hi<<16)|lo of dect, 32 x 512 uints
#define OFF_RACC  10752000   // 32 x 2048
#define OFF_G0    10817536   // 32 x 1024 (unnormalized gU)
#define OFF_G1    10850304   // 32 x 1024
#define OFF_DEN   10883072   // denominators, 2 parity x 32
#define OFF_BAR   10883136
#define OFF_HB16  10883200   // bf16 [32][500][1024] = 8.192M floats
#define ZERO_CNT  163968     // OFF_S .. OFF_BAR+64

using bf16x8 = __attribute__((ext_vector_type(8))) short;
using f32x4  = __attribute__((ext_vector_type(4))) float;

__device__ __forceinline__ f32x4 mfma16(bf16x8 a, bf16x8 b, f32x4 c){
  return __builtin_amdgcn_mfma_f32_16x16x32_bf16(a, b, c, 0, 0, 0);
}
__device__ __forceinline__ unsigned short bfr(float f){
  unsigned x = __float_as_uint(f);
  return (unsigned short)((x + 0x7FFFu + ((x>>16)&1u)) >> 16);
}
__device__ __forceinline__ void bfsplit(float f, short& hi, short& lo){
  unsigned short h = bfr(f);
  float hf = __uint_as_float(((unsigned)h) << 16);
  hi = (short)h;
  lo = (short)bfr(f - hf);
}
__device__ __forceinline__ float bf2f(unsigned short u){
  return __uint_as_float(((unsigned)u) << 16);
}
__device__ __forceinline__ float ftanh(float x){
  float t = fminf(fmaxf(2.f*x, -30.f), 30.f);
  float e = __expf(t);
  return (e - 1.f) / (e + 1.f);
}
__device__ __forceinline__ float fsig(float x){
  float t = fminf(fmaxf(x, -30.f), 30.f);
  return 1.f / (1.f + __expf(-t));
}
__device__ __forceinline__ float gload(const float* p){
  return __hip_atomic_load((float*)p, __ATOMIC_RELAXED, __HIP_MEMORY_SCOPE_AGENT);
}
__device__ __forceinline__ void gstore(float* p, float v){
  __hip_atomic_store(p, v, __ATOMIC_RELAXED, __HIP_MEMORY_SCOPE_AGENT);
}
__device__ __forceinline__ void gstoreu(unsigned* p, unsigned v){
  __hip_atomic_store(p, v, __ATOMIC_RELAXED, __HIP_MEMORY_SCOPE_AGENT);
}
__device__ __forceinline__ void gload2(const float* p, float& a, float& b){
  unsigned long long u = __hip_atomic_load((const unsigned long long*)p,
                          __ATOMIC_RELAXED, __HIP_MEMORY_SCOPE_AGENT);
  a = __uint_as_float((unsigned)u);
  b = __uint_as_float((unsigned)(u >> 32));
}
__device__ __forceinline__ void gloadu2(const unsigned* p, unsigned& a, unsigned& b){
  unsigned long long u = __hip_atomic_load((const unsigned long long*)p,
                          __ATOMIC_RELAXED, __HIP_MEMORY_SCOPE_AGENT);
  a = (unsigned)u;
  b = (unsigned)(u >> 32);
}

// two-level grid barrier (16 groups x 16 blocks), monotonic counters, no cache flush
__device__ __forceinline__ void gridbar(unsigned* bars, unsigned it){
  asm volatile("s_waitcnt vmcnt(0) lgkmcnt(0)" ::: "memory");
  __syncthreads();
  if (threadIdx.x == 0){
    unsigned* gc = bars + 1 + (blockIdx.x & 15);
    unsigned old = __hip_atomic_fetch_add(gc, 1u, __ATOMIC_RELAXED, __HIP_MEMORY_SCOPE_AGENT);
    if (old == it*16u + 15u)
      __hip_atomic_fetch_add(bars, 1u, __ATOMIC_RELAXED, __HIP_MEMORY_SCOPE_AGENT);
    while (__hip_atomic_load(bars, __ATOMIC_RELAXED, __HIP_MEMORY_SCOPE_AGENT) < (it+1u)*16u)
      __builtin_amdgcn_s_sleep(2);
  }
  __syncthreads();
  asm volatile("" ::: "memory");
}

__global__ void k_init(float* __restrict__ ws){
  int i = blockIdx.x * 256 + threadIdx.x;
  if (i < ZERO_CNT) ws[OFF_S + i] = 0.f;
}

// pack Wyy HI-ONLY
__global__ void k_packWyy(const float* __restrict__ Wyy, float* __restrict__ ws){
  unsigned short* wp = (unsigned short*)(ws + OFF_WYYP);
  int t = blockIdx.x * 256 + threadIdx.x;
  if (t >= 625*16*64) return;
  int vt = t / 1024;
  int rem = t - vt*1024;
  int kc = rem >> 6, lane = rem & 63;
  int v  = vt*16 + (lane & 15);
  int k0 = kc*32 + ((lane >> 4) << 3);
  bf16x8 H;
  #pragma unroll
  for (int j = 0; j < 8; ++j) H[j] = (short)bfr(Wyy[(size_t)(k0+j)*V_ + v]);
  *(bf16x8*)(wp + ((size_t)(vt*16 + kc)*64 + lane)*8) = H;
}

// pack Wrec HI-ONLY
__global__ void k_packWrec(const float* __restrict__ Wsy, const float* __restrict__ Wgy,
                           const float* __restrict__ Wsr, const float* __restrict__ Wgr,
                           float* __restrict__ ws){
  unsigned short* wp = (unsigned short*)(ws + OFF_WRECP);
  int t = blockIdx.x * 256 + threadIdx.x;
  if (t >= 160*48*64) return;
  int vt = t / (48*64);
  int rem = t - vt*(48*64);
  int kc = rem >> 6, lane = rem & 63;
  int col = vt*16 + (lane & 15);
  int k0  = kc*32 + ((lane >> 4) << 3);
  bf16x8 H;
  #pragma unroll
  for (int j = 0; j < 8; ++j){
    int k = k0 + j;
    float x;
    if (k < 512) x = (col < 512) ? Wsy[(size_t)k*512 + col] : Wsr[(size_t)k*2048 + (col-512)];
    else         x = (col < 512) ? Wgy[(size_t)(k-512)*512 + col] : Wgr[(size_t)(k-512)*2048 + (col-512)];
    H[j] = (short)bfr(x);
  }
  *(bf16x8*)(wp + ((size_t)(vt*48 + kc)*64 + lane)*8) = H;
}

__global__ void k_packWs(const float* __restrict__ Ws, float* __restrict__ ws){
  unsigned short* wp = (unsigned short*)(ws + OFF_WSB);
  int i = blockIdx.x * 256 + threadIdx.x;
  wp[i] = bfr(Ws[i]);
}

__global__ void k_packHB(const float* __restrict__ hb, float* __restrict__ ws){
  unsigned short* wp = (unsigned short*)(ws + OFF_HB16);
  int i = blockIdx.x * 256 + threadIdx.x;
  if (i < B_*T_*ENC_) wp[i] = bfr(hb[i]);
}

__global__ void k_hproj(const float* __restrict__ A, const float* __restrict__ W,
                        const float* __restrict__ bias, const int* __restrict__ lens,
                        float* __restrict__ ws){
  unsigned short* C = (unsigned short*)(ws + OFF_HPROJ);
  const int bm = blockIdx.x * 64;
  const int bn = blockIdx.y * 64;
  {
    int b0 = bm / T_, t0 = bm % T_;
    int b1 = (bm + 63) / T_;
    if (b0 == b1 && t0 >= lens[b0]) return;
  }
  __shared__ float As[64][33];
  __shared__ float Bs[32][68];
  const int tid = threadIdx.x;
  const int tx = tid & 15, ty = tid >> 4;
  float acc[4][4];
  #pragma unroll
  for (int i = 0; i < 4; ++i)
    #pragma unroll
    for (int j = 0; j < 4; ++j) acc[i][j] = 0.f;
  for (int k0 = 0; k0 < 1024; k0 += 32){
    for (int i = tid; i < 64*32; i += 256){
      int rr = i >> 5, cc = i & 31;
      As[rr][cc] = A[(size_t)(bm + rr) * 1024 + k0 + cc];
    }
    for (int i = tid; i < 32*64; i += 256){
      int rr = i >> 6, cc = i & 63;
      Bs[rr][cc] = W[(size_t)(k0 + rr) * 512 + bn + cc];
    }
    __syncthreads();
    #pragma unroll
    for (int kk = 0; kk < 32; ++kk){
      float a0 = As[ty*4+0][kk], a1 = As[ty*4+1][kk];
      float a2 = As[ty*4+2][kk], a3 = As[ty*4+3][kk];
      float4 b4 = *(const float4*)&Bs[kk][tx*4];
      acc[0][0] += a0*b4.x; acc[0][1] += a0*b4.y; acc[0][2] += a0*b4.z; acc[0][3] += a0*b4.w;
      acc[1][0] += a1*b4.x; acc[1][1] += a1*b4.y; acc[1][2] += a1*b4.z; acc[1][3] += a1*b4.w;
      acc[2][0] += a2*b4.x; acc[2][1] += a2*b4.y; acc[2][2] += a2*b4.z; acc[2][3] += a2*b4.w;
      acc[3][0] += a3*b4.x; acc[3][1] += a3*b4.y; acc[3][2] += a3*b4.z; acc[3][3] += a3*b4.w;
    }
    __syncthreads();
  }
  #pragma unroll
  for (int i = 0; i < 4; ++i){
    int m = bm + ty*4 + i;
    ushort4 o;
    o.x = bfr(acc[i][0] + bias[bn + tx*4 + 0]);
    o.y = bfr(acc[i][1] + bias[bn + tx*4 + 1]);
    o.z = bfr(acc[i][2] + bias[bn + tx*4 + 2]);
    o.w = bfr(acc[i][3] + bias[bn + tx*4 + 3]);
    *(ushort4*)&C[(size_t)m * 512 + bn + tx*4] = o;
  }
}

__global__ __launch_bounds__(NT_, 1) void k_persist(
    const int* __restrict__ lens,
    const int* __restrict__ labels, const float* __restrict__ av,
    const float* __restrict__ bsy, const float* __restrict__ bgy,
    const float* __restrict__ byy,
    const float* __restrict__ Eyr,
    const float* __restrict__ bsr, const float* __restrict__ bgr,
    float* __restrict__ out, float* __restrict__ ws)
{
  const int blk = blockIdx.x;
  const int tid = threadIdx.x;
  const int w   = tid >> 6;      // 0..15
  const int lane= tid & 63;
  unsigned* bars = (unsigned*)(ws + OFF_BAR);
  const unsigned short* wyyp  = (const unsigned short*)(ws + OFF_WYYP);
  const unsigned short* wrecp = (const unsigned short*)(ws + OFF_WRECP);
  const unsigned short* wsb   = (const unsigned short*)(ws + OFF_WSB);
  const unsigned short* hpB   = (const unsigned short*)(ws + OFF_HPROJ);
  const unsigned short* hb16  = (const unsigned short*)(ws + OFF_HB16);
  unsigned* dectP = (unsigned*)(ws + OFF_DECTP);
  unsigned* sP    = (unsigned*)(ws + OFF_S);
  __shared__ __align__(16) float smem[16512];   // 66 KB (reused per phase)

  const int arow  = lane & 15;
  const int klane = (lane >> 4) << 3;
  float c_reg = 0.f;

  for (int l = 0; l <= L_; ++l){
    const int p = l & 1;
    const int goff = p ? OFF_G1 : OFF_G0;
    // ===== X: vocab(l-1) [0..156] || state {LSTM,sws,wexp,scan} [157..220] =====
    if (blk < 157){
      if (l > 0){
        // stage dectP -> LDS [32][516] uints
        unsigned* dst = (unsigned*)smem;
        for (int i = tid; i < 8192; i += NT_){
          int row = i >> 8, k2 = (i & 255) << 1;
          unsigned a, b;
          gloadu2(dectP + row*H_ + k2, a, b);
          dst[row*516 + k2]     = a;
          dst[row*516 + k2 + 1] = b;
        }
        __syncthreads();
        const int vtslot = w >> 2;           // 0..3
        const int khq    = w & 3;            // 0..3 (4 kc each)
        const int vt = blk*4 + vtslot;
        f32x4 a0 = {0.f,0.f,0.f,0.f}, a1 = {0.f,0.f,0.f,0.f};
        if (vt < 625){
          #pragma unroll
          for (int kc2 = 0; kc2 < 4; ++kc2){
            const int kc = khq*4 + kc2;
            const int k0 = kc*32 + klane;
            bf16x8 Ahi0, Alo0, Ahi1, Alo1;
            {
              const unsigned* dp = dst + arow*516 + k0;
              uint4 qa = *(const uint4*)(dp);
              uint4 qb = *(const uint4*)(dp+4);
              unsigned q[8] = {qa.x,qa.y,qa.z,qa.w,qb.x,qb.y,qb.z,qb.w};
              #pragma unroll
              for (int j = 0; j < 8; ++j){
                Ahi0[j] = (short)(q[j] >> 16);
                Alo0[j] = (short)(q[j] & 0xFFFFu);
              }
            }
            {
              const unsigned* dp = dst + (arow+16)*516 + k0;
              uint4 qa = *(const uint4*)(dp);
              uint4 qb = *(const uint4*)(dp+4);
              unsigned q[8] = {qa.x,qa.y,qa.z,qa.w,qb.x,qb.y,qb.z,qb.w};
              #pragma unroll
              for (int j = 0; j < 8; ++j){
                Ahi1[j] = (short)(q[j] >> 16);
                Alo1[j] = (short)(q[j] & 0xFFFFu);
              }
            }
            bf16x8 Bv = *(const bf16x8*)(wyyp + ((size_t)(vt*16 + kc)*64 + lane)*8);
            a0 = mfma16(Ahi0, Bv, a0);
            a0 = mfma16(Alo0, Bv, a0);
            a1 = mfma16(Ahi1, Bv, a1);
            a1 = mfma16(Alo1, Bv, a1);
          }
        }
        __syncthreads();   // all dst reads done; reuse smem for reduction
        #pragma unroll
        for (int r = 0; r < 4; ++r){
          smem[((vtslot*4 + khq)*2 + 0)*256 + lane*4 + r] = a0[r];
          smem[((vtslot*4 + khq)*2 + 1)*256 + lane*4 + r] = a1[r];
        }
        __syncthreads();
        const int lv = l - 1;
        #pragma unroll
        for (int oo = 0; oo < 2; ++oo){
          const int q   = tid + oo*NT_;           // 0..2047
          const int vts = q >> 9;
          const int rem = q & 511;
          const int bt  = rem >> 8;
          const int r8  = rem & 255;
          const int vto = blk*4 + vts;
          if (vto < 625){
            float v = 0.f;
            #pragma unroll
            for (int kq = 0; kq < 4; ++kq)
              v += smem[((vts*4 + kq)*2 + bt)*256 + r8];
            const int ln = r8 >> 2, rr = r8 & 3;
            const int row = bt*16 + ((ln >> 4) << 2) + rr;
            const int vcol = vto*16 + (ln & 15);
            out[((size_t)row*L_ + lv)*V_ + vcol] = v + byy[vcol];
          }
        }
        __syncthreads();
      }
    } else if (blk < 221){
      if (l < L_){
        const int u = blk - 157;
        const int b = u >> 1, half = u & 1;
        float* ssm  = smem;           // 512: s[b,:]
        float* part = smem + 512;     // 1024: sws partials
        float* wsm  = smem + 1536;    // 512: sws[b,:]
        float* ex   = smem + 2048;    // 256: this block's wexp values
        float* pg   = smem + 2304;    // 8 x 1024 scan partials
        if (l == 0){
          if (tid < 512){ ssm[tid] = 0.f; c_reg = 0.f; }
        } else {
          if (tid < 512){
            const int h = tid;
            const float* ey = Eyr + (size_t)labels[b*L_ + (l-1)] * H4_;
            float ri = gload(&ws[OFF_RACC + b*H4_ + h])        + bsr[h]      + bgr[h]      + ey[h];
            float rf = gload(&ws[OFF_RACC + b*H4_ + 512 + h])  + bsr[512+h]  + bgr[512+h]  + ey[512+h];
            float rg = gload(&ws[OFF_RACC + b*H4_ + 1024 + h]) + bsr[1024+h] + bgr[1024+h] + ey[1024+h];
            float ro = gload(&ws[OFF_RACC + b*H4_ + 1536 + h]) + bsr[1536+h] + bgr[1536+h] + ey[1536+h];
            float cn = fsig(rf)*c_reg + fsig(ri)*ftanh(rg);
            float sn = fsig(ro)*ftanh(cn);
            c_reg = cn;
            if (half == 0){
              short h_, lo_; bfsplit(sn, h_, lo_);
              gstoreu(&sP[b*H_ + h], ((unsigned)(unsigned short)h_ << 16) | (unsigned)(unsigned short)lo_);
            }
            ssm[h] = sn;
          }
        }
        __syncthreads();
        // sws[b,:] = s @ Ws (bf16 Ws, L2-resident); 2 k-halves x 1 col/thread
        {
          const int col  = tid & 511;
          const int ksec = tid >> 9;        // 0..1
          const float* sp = ssm + ksec*256;
          const unsigned short* wb = wsb + (size_t)(ksec*256)*512 + col;
          float acc = 0.f;
          for (int k = 0; k < 256; k += 8){
            float4 s0 = *(const float4*)&sp[k];
            float4 s1 = *(const float4*)&sp[k+4];
            float wv[8];
            #pragma unroll
            for (int j = 0; j < 8; ++j)
              wv[j] = bf2f(wb[(size_t)(k+j)*512]);
            acc += s0.x*wv[0] + s0.y*wv[1] + s0.z*wv[2] + s0.w*wv[3]
                 + s1.x*wv[4] + s1.y*wv[5] + s1.z*wv[6] + s1.w*wv[7];
          }
          part[ksec*512 + col] = acc;
        }
        __syncthreads();
        if (tid < 512) wsm[tid] = part[tid] + part[512 + tid];
        __syncthreads();
        // wexp for t = 2w + half + 32i -> ex[w + 16i]  (LDS only)
        const int len = lens[b];
        {
          float avr[8], swr[8];
          #pragma unroll
          for (int j = 0; j < 8; ++j){
            avr[j] = av[lane*8 + j];
            swr[j] = wsm[lane*8 + j];
          }
          for (int t = 2*w + half; t < len; t += 32){
            bf16x8 hp = *(const bf16x8*)&hpB[(size_t)(b*T_ + t)*512 + lane*8];
            float sum = 0.f;
            #pragma unroll
            for (int j = 0; j < 8; ++j)
              sum += avr[j] * ftanh(bf2f((unsigned short)hp[j]) + swr[j]);
            #pragma unroll
            for (int off = 32; off > 0; off >>= 1) sum += __shfl_xor(sum, off, 64);
            if (lane == 0) ex[(t - half) >> 1] = __expf(sum);
          }
        }
        __syncthreads();
        const int n = (len - half + 1) >> 1;   // count of this block's t values
        // denominator partial
        if (tid < 64){
          float s2 = 0.f;
          for (int i = tid; i < n; i += 64) s2 += ex[i];
          #pragma unroll
          for (int off = 32; off > 0; off >>= 1) s2 += __shfl_xor(s2, off, 64);
          if (tid == 0 && n > 0) atomicAdd(&ws[OFF_DEN + p*32 + b], s2);
        }
        // scan this block's t set over hb16 (bf16, cached); 8 t-groups
        {
          const int tg = tid >> 7;        // 0..7
          const int cl = tid & 127;
          const int col0 = cl*8;
          const unsigned short* hp = hb16 + (size_t)b*T_*ENC_ + col0;
          float acc[8] = {0.f,0.f,0.f,0.f,0.f,0.f,0.f,0.f};
          for (int idx = tg; idx < n; idx += 8){
            const int t = half + 2*idx;
            bf16x8 x = *(const bf16x8*)&hp[(size_t)t * ENC_];
            float a = ex[idx];
            #pragma unroll
            for (int j = 0; j < 8; ++j) acc[j] += a * bf2f((unsigned short)x[j]);
          }
          *(float4*)&pg[tg*1024 + col0]     = *(float4*)&acc[0];
          *(float4*)&pg[tg*1024 + col0 + 4] = *(float4*)&acc[4];
        }
        __syncthreads();
        if (tid < 256 && n > 0){
          const int c0 = tid*4;
          #pragma unroll
          for (int j = 0; j < 4; ++j){
            float s = pg[c0+j] + pg[1024+c0+j] + pg[2048+c0+j] + pg[3072+c0+j]
                    + pg[4096+c0+j] + pg[5120+c0+j] + pg[6144+c0+j] + pg[7168+c0+j];
            atomicAdd(&ws[goff + b*ENC_ + c0 + j], s);
          }
        }
      }
    }
    if (l == L_) break;     // uniform exit
    gridbar(bars, (unsigned)(l*2 + 0));

    // ===== Y: [dect|racc] = [sP | gU/den] @ WrecHi (160 blocks, 1 vt, 16 waves) =====
    if (blk < 160){
      const float invb0 = 1.f / gload(&ws[OFF_DEN + p*32 + arow]);
      const float invb1 = 1.f / gload(&ws[OFF_DEN + p*32 + arow + 16]);
      const int vt = blk;
      f32x4 acc0 = {0.f,0.f,0.f,0.f}, acc1 = {0.f,0.f,0.f,0.f};
      #pragma unroll
      for (int j3 = 0; j3 < 3; ++j3){
        const int kc = w*3 + j3;
        const int k0 = kc*32 + klane;
        const bool isg = (k0 >= 512);
        bf16x8 Ahi0, Alo0, Ahi1, Alo1;
        if (!isg){
          unsigned q[8];
          const unsigned* dp = sP + arow*H_ + k0;
          gloadu2(dp+0, q[0], q[1]);
          gloadu2(dp+2, q[2], q[3]);
          gloadu2(dp+4, q[4], q[5]);
          gloadu2(dp+6, q[6], q[7]);
          #pragma unroll
          for (int j = 0; j < 8; ++j){
            Ahi0[j] = (short)(q[j] >> 16);
            Alo0[j] = (short)(q[j] & 0xFFFFu);
          }
          const unsigned* dp1 = sP + (arow+16)*H_ + k0;
          gloadu2(dp1+0, q[0], q[1]);
          gloadu2(dp1+2, q[2], q[3]);
          gloadu2(dp1+4, q[4], q[5]);
          gloadu2(dp1+6, q[6], q[7]);
          #pragma unroll
          for (int j = 0; j < 8; ++j){
            Ahi1[j] = (short)(q[j] >> 16);
            Alo1[j] = (short)(q[j] & 0xFFFFu);
          }
        } else {
          {
            const float* src = &ws[goff + arow*ENC_ + (k0 - 512)];
            float x[8];
            gload2(src+0, x[0], x[1]);
            gload2(src+2, x[2], x[3]);
            gload2(src+4, x[4], x[5]);
            gload2(src+6, x[6], x[7]);
            #pragma unroll
            for (int j = 0; j < 8; ++j){
              short h, lo; bfsplit(x[j]*invb0, h, lo);
              Ahi0[j] = h; Alo0[j] = lo;
            }
          }
          {
            const float* src = &ws[goff + (arow+16)*ENC_ + (k0 - 512)];
            float x[8];
            gload2(src+0, x[0], x[1]);
            gload2(src+2, x[2], x[3]);
            gload2(src+4, x[4], x[5]);
            gload2(src+6, x[6], x[7]);
            #pragma unroll
            for (int j = 0; j < 8; ++j){
              short h, lo; bfsplit(x[j]*invb1, h, lo);
              Ahi1[j] = h; Alo1[j] = lo;
            }
          }
        }
        bf16x8 Bv = *(const bf16x8*)(wrecp + ((size_t)(vt*48 + kc)*64 + lane)*8);
        acc0 = mfma16(Ahi0, Bv, acc0);
        acc0 = mfma16(Alo0, Bv, acc0);
        acc1 = mfma16(Ahi1, Bv, acc1);
        acc1 = mfma16(Alo1, Bv, acc1);
      }
      // staged reduce across 16 k-waves: smem[w][rg][256]
      #pragma unroll
      for (int r = 0; r < 4; ++r){
        smem[(w*2 + 0)*256 + lane*4 + r] = acc0[r];
        smem[(w*2 + 1)*256 + lane*4 + r] = acc1[r];
      }
      __syncthreads();
      if (tid < 512){
        const int bt = tid >> 8, r8 = tid & 255;
        float v = 0.f;
        #pragma unroll
        for (int w16 = 0; w16 < 16; ++w16)
          v += smem[(w16*2 + bt)*256 + r8];
        const int ln = r8 >> 2, rr = r8 & 3;
        const int row = bt*16 + ((ln >> 4) << 2) + rr;
        const int col = blk*16 + (ln & 15);
        if (col < 512){
          float t = ftanh(v + bsy[col] + bgy[col]);
          unsigned short hi_ = bfr(t);
          unsigned short lo_ = bfr(t - bf2f(hi_));
          gstoreu(&dectP[row*H_ + col], ((unsigned)hi_ << 16) | lo_);
        } else {
          gstore(&ws[OFF_RACC + row*H4_ + (col - 512)], v);
        }
      }
    } else if (blk < 176){
      // zero next parity gU and den
      const int zoff = p ? OFF_G0 : OFF_G1;
      for (int i = (blk - 160)*NT_ + tid; i < B_*ENC_; i += 16*NT_)
        gstore(&ws[zoff + i], 0.f);
      if (blk == 160 && tid < 32)
        gstore(&ws[OFF_DEN + (p^1)*32 + tid], 0.f);
    }
    gridbar(bars, (unsigned)(l*2 + 1));
  }
}

extern "C" void kernel_launch(void* const* d_in, const int* in_sizes, int n_in,
                              void* d_out, int out_size, void* d_ws, size_t ws_size,
                              hipStream_t stream){
  const float* h_batch = (const float*)d_in[0];
  const int*   seq_lens= (const int*)d_in[1];
  const int*   labels  = (const int*)d_in[2];
  const float* attn_Ws = (const float*)d_in[3];
  const float* attn_Wh = (const float*)d_in[4];
  const float* attn_b  = (const float*)d_in[5];
  const float* attn_v  = (const float*)d_in[6];
  const float* W_sy    = (const float*)d_in[7];
  const float* b_sy    = (const float*)d_in[8];
  const float* W_gy    = (const float*)d_in[9];
  const float* b_gy    = (const float*)d_in[10];
  const float* W_yy    = (const float*)d_in[11];
  const float* b_yy    = (const float*)d_in[12];
  const float* E_yr    = (const float*)d_in[13];
  const float* W_sr    = (const float*)d_in[14];
  const float* b_sr    = (const float*)d_in[15];
  const float* W_gr    = (const float*)d_in[16];
  const float* b_gr    = (const float*)d_in[17];
  float* out = (float*)d_out;
  float* ws  = (float*)d_ws;

  k_init    <<<641, 256, 0, stream>>>(ws);
  k_packWyy <<<2500, 256, 0, stream>>>(W_yy, ws);
  k_packWrec<<<1920, 256, 0, stream>>>(W_sy, W_gy, W_sr, W_gr, ws);
  k_packWs  <<<1024, 256, 0, stream>>>(attn_Ws, ws);
  k_packHB  <<<64000, 256, 0, stream>>>(h_batch, ws);
  k_hproj   <<<dim3(250, 8), 256, 0, stream>>>(h_batch, attn_Wh, attn_b, seq_lens, ws);

  void* kargs[] = {
    (void*)&seq_lens, (void*)&labels, (void*)&attn_v,
    (void*)&b_sy, (void*)&b_gy, (void*)&b_yy,
    (void*)&E_yr, (void*)&b_sr, (void*)&b_gr,
    (void*)&out, (void*)&ws
  };
  hipLaunchCooperativeKernel((void*)k_persist, dim3(NB_), dim3(NT_), kargs, 0, stream);
}

// Round 17
// 9117.635 us; speedup vs baseline: 1.9819x; 1.9819x over previous
//
#include <hip/hip_runtime.h>
#include <cstdint>

#define B_   32
#define T_   500
#define H_   512
#define ENC_ 1024
#define V_   10000
#define L_   100
#define H4_  2048
#define NB_  256
#define NT_  512

// workspace layout (float offsets)
#define OFF_HPROJ 0          // bf16 [16000][512]
#define OFF_WYYP  4096000    // bf16 HI-ONLY [625 vt][16 kc][64][8]
#define OFF_WRECP 6656000    // bf16 HI-ONLY [160 vt][48 kc][64][8]
#define OFF_WSB   10588160   // bf16 [512 k][512 col]
#define OFF_S     10719232   // packed (bf16hi<<16)|lo of s, 32 x 512 uints
#define OFF_DECTP 10735616   // packed (bf16hi<<16)|lo of dect, 32 x 512 uints
#define OFF_RACC  10752000   // 32 x 2048
#define OFF_G0    10817536   // 32 x 1024 (unnormalized gU)
#define OFF_G1    10850304   // 32 x 1024
#define OFF_DEN   10883072   // denominators, 2 parity x 32
#define OFF_BAR   10883136
#define OFF_HB16  10883200   // bf16 [32][500][1024] = 8.192M floats
#define ZERO_CNT  163968     // OFF_S .. OFF_BAR+64

using bf16x8 = __attribute__((ext_vector_type(8))) short;
using f32x4  = __attribute__((ext_vector_type(4))) float;

__device__ __forceinline__ f32x4 mfma16(bf16x8 a, bf16x8 b, f32x4 c){
  return __builtin_amdgcn_mfma_f32_16x16x32_bf16(a, b, c, 0, 0, 0);
}
__device__ __forceinline__ unsigned short bfr(float f){
  unsigned x = __float_as_uint(f);
  return (unsigned short)((x + 0x7FFFu + ((x>>16)&1u)) >> 16);
}
__device__ __forceinline__ void bfsplit(float f, short& hi, short& lo){
  unsigned short h = bfr(f);
  float hf = __uint_as_float(((unsigned)h) << 16);
  hi = (short)h;
  lo = (short)bfr(f - hf);
}
__device__ __forceinline__ float bf2f(unsigned short u){
  return __uint_as_float(((unsigned)u) << 16);
}
__device__ __forceinline__ float ftanh(float x){
  float t = fminf(fmaxf(2.f*x, -30.f), 30.f);
  float e = __expf(t);
  return (e - 1.f) / (e + 1.f);
}
__device__ __forceinline__ float fsig(float x){
  float t = fminf(fmaxf(x, -30.f), 30.f);
  return 1.f / (1.f + __expf(-t));
}
__device__ __forceinline__ float gload(const float* p){
  return __hip_atomic_load((float*)p, __ATOMIC_RELAXED, __HIP_MEMORY_SCOPE_AGENT);
}
__device__ __forceinline__ void gstore(float* p, float v){
  __hip_atomic_store(p, v, __ATOMIC_RELAXED, __HIP_MEMORY_SCOPE_AGENT);
}
__device__ __forceinline__ void gstoreu(unsigned* p, unsigned v){
  __hip_atomic_store(p, v, __ATOMIC_RELAXED, __HIP_MEMORY_SCOPE_AGENT);
}
__device__ __forceinline__ void gload2(const float* p, float& a, float& b){
  unsigned long long u = __hip_atomic_load((const unsigned long long*)p,
                          __ATOMIC_RELAXED, __HIP_MEMORY_SCOPE_AGENT);
  a = __uint_as_float((unsigned)u);
  b = __uint_as_float((unsigned)(u >> 32));
}
__device__ __forceinline__ void gloadu2(const unsigned* p, unsigned& a, unsigned& b){
  unsigned long long u = __hip_atomic_load((const unsigned long long*)p,
                          __ATOMIC_RELAXED, __HIP_MEMORY_SCOPE_AGENT);
  a = (unsigned)u;
  b = (unsigned)(u >> 32);
}

// two-level grid barrier (16 groups x 16 blocks), monotonic counters, no cache flush
__device__ __forceinline__ void gridbar(unsigned* bars, unsigned it){
  asm volatile("s_waitcnt vmcnt(0) lgkmcnt(0)" ::: "memory");
  __syncthreads();
  if (threadIdx.x == 0){
    unsigned* gc = bars + 1 + (blockIdx.x & 15);
    unsigned old = __hip_atomic_fetch_add(gc, 1u, __ATOMIC_RELAXED, __HIP_MEMORY_SCOPE_AGENT);
    if (old == it*16u + 15u)
      __hip_atomic_fetch_add(bars, 1u, __ATOMIC_RELAXED, __HIP_MEMORY_SCOPE_AGENT);
    while (__hip_atomic_load(bars, __ATOMIC_RELAXED, __HIP_MEMORY_SCOPE_AGENT) < (it+1u)*16u)
      __builtin_amdgcn_s_sleep(2);
  }
  __syncthreads();
  asm volatile("" ::: "memory");
}

__global__ void k_init(float* __restrict__ ws){
  int i = blockIdx.x * 256 + threadIdx.x;
  if (i < ZERO_CNT) ws[OFF_S + i] = 0.f;
}

// pack Wyy HI-ONLY
__global__ void k_packWyy(const float* __restrict__ Wyy, float* __restrict__ ws){
  unsigned short* wp = (unsigned short*)(ws + OFF_WYYP);
  int t = blockIdx.x * 256 + threadIdx.x;
  if (t >= 625*16*64) return;
  int vt = t / 1024;
  int rem = t - vt*1024;
  int kc = rem >> 6, lane = rem & 63;
  int v  = vt*16 + (lane & 15);
  int k0 = kc*32 + ((lane >> 4) << 3);
  bf16x8 H;
  #pragma unroll
  for (int j = 0; j < 8; ++j) H[j] = (short)bfr(Wyy[(size_t)(k0+j)*V_ + v]);
  *(bf16x8*)(wp + ((size_t)(vt*16 + kc)*64 + lane)*8) = H;
}

// pack Wrec HI-ONLY
__global__ void k_packWrec(const float* __restrict__ Wsy, const float* __restrict__ Wgy,
                           const float* __restrict__ Wsr, const float* __restrict__ Wgr,
                           float* __restrict__ ws){
  unsigned short* wp = (unsigned short*)(ws + OFF_WRECP);
  int t = blockIdx.x * 256 + threadIdx.x;
  if (t >= 160*48*64) return;
  int vt = t / (48*64);
  int rem = t - vt*(48*64);
  int kc = rem >> 6, lane = rem & 63;
  int col = vt*16 + (lane & 15);
  int k0  = kc*32 + ((lane >> 4) << 3);
  bf16x8 H;
  #pragma unroll
  for (int j = 0; j < 8; ++j){
    int k = k0 + j;
    float x;
    if (k < 512) x = (col < 512) ? Wsy[(size_t)k*512 + col] : Wsr[(size_t)k*2048 + (col-512)];
    else         x = (col < 512) ? Wgy[(size_t)(k-512)*512 + col] : Wgr[(size_t)(k-512)*2048 + (col-512)];
    H[j] = (short)bfr(x);
  }
  *(bf16x8*)(wp + ((size_t)(vt*48 + kc)*64 + lane)*8) = H;
}

__global__ void k_packWs(const float* __restrict__ Ws, float* __restrict__ ws){
  unsigned short* wp = (unsigned short*)(ws + OFF_WSB);
  int i = blockIdx.x * 256 + threadIdx.x;
  wp[i] = bfr(Ws[i]);
}

__global__ void k_packHB(const float* __restrict__ hb, float* __restrict__ ws){
  unsigned short* wp = (unsigned short*)(ws + OFF_HB16);
  int i = blockIdx.x * 256 + threadIdx.x;
  if (i < B_*T_*ENC_) wp[i] = bfr(hb[i]);
}

__global__ void k_hproj(const float* __restrict__ A, const float* __restrict__ W,
                        const float* __restrict__ bias, const int* __restrict__ lens,
                        float* __restrict__ ws){
  unsigned short* C = (unsigned short*)(ws + OFF_HPROJ);
  const int bm = blockIdx.x * 64;
  const int bn = blockIdx.y * 64;
  {
    int b0 = bm / T_, t0 = bm % T_;
    int b1 = (bm + 63) / T_;
    if (b0 == b1 && t0 >= lens[b0]) return;
  }
  __shared__ float As[64][33];
  __shared__ float Bs[32][68];
  const int tid = threadIdx.x;
  const int tx = tid & 15, ty = tid >> 4;
  float acc[4][4];
  #pragma unroll
  for (int i = 0; i < 4; ++i)
    #pragma unroll
    for (int j = 0; j < 4; ++j) acc[i][j] = 0.f;
  for (int k0 = 0; k0 < 1024; k0 += 32){
    for (int i = tid; i < 64*32; i += 256){
      int rr = i >> 5, cc = i & 31;
      As[rr][cc] = A[(size_t)(bm + rr) * 1024 + k0 + cc];
    }
    for (int i = tid; i < 32*64; i += 256){
      int rr = i >> 6, cc = i & 63;
      Bs[rr][cc] = W[(size_t)(k0 + rr) * 512 + bn + cc];
    }
    __syncthreads();
    #pragma unroll
    for (int kk = 0; kk < 32; ++kk){
      float a0 = As[ty*4+0][kk], a1 = As[ty*4+1][kk];
      float a2 = As[ty*4+2][kk], a3 = As[ty*4+3][kk];
      float4 b4 = *(const float4*)&Bs[kk][tx*4];
      acc[0][0] += a0*b4.x; acc[0][1] += a0*b4.y; acc[0][2] += a0*b4.z; acc[0][3] += a0*b4.w;
      acc[1][0] += a1*b4.x; acc[1][1] += a1*b4.y; acc[1][2] += a1*b4.z; acc[1][3] += a1*b4.w;
      acc[2][0] += a2*b4.x; acc[2][1] += a2*b4.y; acc[2][2] += a2*b4.z; acc[2][3] += a2*b4.w;
      acc[3][0] += a3*b4.x; acc[3][1] += a3*b4.y; acc[3][2] += a3*b4.z; acc[3][3] += a3*b4.w;
    }
    __syncthreads();
  }
  #pragma unroll
  for (int i = 0; i < 4; ++i){
    int m = bm + ty*4 + i;
    ushort4 o;
    o.x = bfr(acc[i][0] + bias[bn + tx*4 + 0]);
    o.y = bfr(acc[i][1] + bias[bn + tx*4 + 1]);
    o.z = bfr(acc[i][2] + bias[bn + tx*4 + 2]);
    o.w = bfr(acc[i][3] + bias[bn + tx*4 + 3]);
    *(ushort4*)&C[(size_t)m * 512 + bn + tx*4] = o;
  }
}

__global__ __launch_bounds__(NT_, 2) void k_persist(
    const int* __restrict__ lens,
    const int* __restrict__ labels, const float* __restrict__ av,
    const float* __restrict__ bsy, const float* __restrict__ bgy,
    const float* __restrict__ byy,
    const float* __restrict__ Eyr,
    const float* __restrict__ bsr, const float* __restrict__ bgr,
    float* __restrict__ out, float* __restrict__ ws)
{
  const int blk = blockIdx.x;
  const int tid = threadIdx.x;
  const int w   = tid >> 6;      // 0..7
  const int lane= tid & 63;
  unsigned* bars = (unsigned*)(ws + OFF_BAR);
  const unsigned short* wyyp  = (const unsigned short*)(ws + OFF_WYYP);
  const unsigned short* wrecp = (const unsigned short*)(ws + OFF_WRECP);
  const unsigned short* wsb   = (const unsigned short*)(ws + OFF_WSB);
  const unsigned short* hpB   = (const unsigned short*)(ws + OFF_HPROJ);
  const unsigned short* hb16  = (const unsigned short*)(ws + OFF_HB16);
  unsigned* dectP = (unsigned*)(ws + OFF_DECTP);
  unsigned* sP    = (unsigned*)(ws + OFF_S);
  __shared__ __align__(16) float smem[18688];   // 74.75 KB

  const int arow  = lane & 15;
  const int klane = (lane >> 4) << 3;
  float c_reg = 0.f;

  for (int l = 0; l <= L_; ++l){
    const int p = l & 1;
    const int goff = p ? OFF_G1 : OFF_G0;
    // ===== X: vocab(l-1) [0..156] || state [157..220] || zero next parity [221..255] =====
    if (blk < 157){
      if (l > 0){
        // stage dectP -> LDS [32][516] uints
        unsigned* dst = (unsigned*)smem;
        for (int i = tid; i < 8192; i += NT_){
          int row = i >> 8, k2 = (i & 255) << 1;
          unsigned a, b;
          gloadu2(dectP + row*H_ + k2, a, b);
          dst[row*516 + k2]     = a;
          dst[row*516 + k2 + 1] = b;
        }
        __syncthreads();
        const int kh = w & 1;
        const int vtslot = w >> 1;           // 0..3
        const int vt = blk*4 + vtslot;
        f32x4 a0 = {0.f,0.f,0.f,0.f}, a1 = {0.f,0.f,0.f,0.f};
        if (vt < 625){
          for (int kc2 = 0; kc2 < 8; ++kc2){
            const int kc = kh*8 + kc2;
            const int k0 = kc*32 + klane;
            bf16x8 Ahi0, Alo0, Ahi1, Alo1;
            {
              const unsigned* dp = dst + arow*516 + k0;
              uint4 qa = *(const uint4*)(dp);
              uint4 qb = *(const uint4*)(dp+4);
              unsigned q[8] = {qa.x,qa.y,qa.z,qa.w,qb.x,qb.y,qb.z,qb.w};
              #pragma unroll
              for (int j = 0; j < 8; ++j){
                Ahi0[j] = (short)(q[j] >> 16);
                Alo0[j] = (short)(q[j] & 0xFFFFu);
              }
            }
            {
              const unsigned* dp = dst + (arow+16)*516 + k0;
              uint4 qa = *(const uint4*)(dp);
              uint4 qb = *(const uint4*)(dp+4);
              unsigned q[8] = {qa.x,qa.y,qa.z,qa.w,qb.x,qb.y,qb.z,qb.w};
              #pragma unroll
              for (int j = 0; j < 8; ++j){
                Ahi1[j] = (short)(q[j] >> 16);
                Alo1[j] = (short)(q[j] & 0xFFFFu);
              }
            }
            bf16x8 Bv = *(const bf16x8*)(wyyp + ((size_t)(vt*16 + kc)*64 + lane)*8);
            a0 = mfma16(Ahi0, Bv, a0);
            a0 = mfma16(Alo0, Bv, a0);
            a1 = mfma16(Ahi1, Bv, a1);
            a1 = mfma16(Alo1, Bv, a1);
          }
        }
        float* red = smem + 16512;           // 4 x 512
        if (vt < 625 && kh == 0){
          #pragma unroll
          for (int r = 0; r < 4; ++r){
            red[vtslot*512 +       lane*4 + r] = a0[r];
            red[vtslot*512 + 256 + lane*4 + r] = a1[r];
          }
        }
        __syncthreads();
        if (vt < 625 && kh == 1){
          const int v = vt*16 + arow;
          const float bv = byy[v];
          const int lv = l - 1;
          #pragma unroll
          for (int r = 0; r < 4; ++r){
            const int row0 = ((lane >> 4) << 2) + r;
            float v0 = red[vtslot*512 +       lane*4 + r] + a0[r] + bv;
            float v1 = red[vtslot*512 + 256 + lane*4 + r] + a1[r] + bv;
            out[((size_t)(row0)*L_      + lv)*V_ + v] = v0;
            out[((size_t)(row0 + 16)*L_ + lv)*V_ + v] = v1;
          }
        }
        __syncthreads();
      }
    } else if (blk < 221){
      if (l < L_){
        const int u = blk - 157;
        const int b = u >> 1, half = u & 1;
        float* ssm  = smem;           // 512: s[b,:]
        float* part = smem + 512;     // 2048: sws partials
        float* wsm  = smem + 2560;    // 512: sws[b,:]
        float* ex   = smem + 3072;    // 256: this block's wexp values
        float* pg   = smem + 3328;    // 4 x 1024 scan partials
        if (l == 0){
          ssm[tid] = 0.f;
          c_reg = 0.f;
        } else {
          const int h = tid;
          const float* ey = Eyr + (size_t)labels[b*L_ + (l-1)] * H4_;
          float ri = gload(&ws[OFF_RACC + b*H4_ + h])        + bsr[h]      + bgr[h]      + ey[h];
          float rf = gload(&ws[OFF_RACC + b*H4_ + 512 + h])  + bsr[512+h]  + bgr[512+h]  + ey[512+h];
          float rg = gload(&ws[OFF_RACC + b*H4_ + 1024 + h]) + bsr[1024+h] + bgr[1024+h] + ey[1024+h];
          float ro = gload(&ws[OFF_RACC + b*H4_ + 1536 + h]) + bsr[1536+h] + bgr[1536+h] + ey[1536+h];
          float cn = fsig(rf)*c_reg + fsig(ri)*ftanh(rg);
          float sn = fsig(ro)*ftanh(cn);
          c_reg = cn;
          if (half == 0){
            short h_, lo_; bfsplit(sn, h_, lo_);
            gstoreu(&sP[b*H_ + h], ((unsigned)(unsigned short)h_ << 16) | (unsigned)(unsigned short)lo_);
          }
          ssm[h] = sn;
        }
        __syncthreads();
        // sws[b,:] = s @ Ws (bf16 Ws, L2-resident)
        {
          const int colp = tid & 255;
          const int kh2  = tid >> 8;
          const int col0 = colp*2;
          const float* sp = ssm + kh2*256;
          const unsigned short* wb = wsb + (size_t)(kh2*256)*512 + col0;
          float acc0 = 0.f, acc1 = 0.f;
          for (int k = 0; k < 256; k += 8){
            float4 s0 = *(const float4*)&sp[k];
            float4 s1 = *(const float4*)&sp[k+4];
            unsigned wv[8];
            #pragma unroll
            for (int j = 0; j < 8; ++j)
              wv[j] = *(const unsigned*)&wb[(size_t)(k+j)*512];
            float sv[8] = {s0.x,s0.y,s0.z,s0.w,s1.x,s1.y,s1.z,s1.w};
            #pragma unroll
            for (int j = 0; j < 8; ++j){
              acc0 += sv[j] * bf2f((unsigned short)(wv[j] & 0xFFFFu));
              acc1 += sv[j] * bf2f((unsigned short)(wv[j] >> 16));
            }
          }
          part[kh2*1024 + col0]     = acc0;
          part[kh2*1024 + col0 + 1] = acc1;
        }
        __syncthreads();
        wsm[tid] = part[tid] + part[1024 + tid];
        __syncthreads();
        // wexp for t = 2w + half + 16i -> ex[w + 8i]  (in LDS only)
        const int len = lens[b];
        {
          float avr[8], swr[8];
          #pragma unroll
          for (int j = 0; j < 8; ++j){
            avr[j] = av[lane*8 + j];
            swr[j] = wsm[lane*8 + j];
          }
          for (int t = 2*w + half; t < len; t += 16){
            bf16x8 hp = *(const bf16x8*)&hpB[(size_t)(b*T_ + t)*512 + lane*8];
            float sum = 0.f;
            #pragma unroll
            for (int j = 0; j < 8; ++j)
              sum += avr[j] * ftanh(bf2f((unsigned short)hp[j]) + swr[j]);
            #pragma unroll
            for (int off = 32; off > 0; off >>= 1) sum += __shfl_xor(sum, off, 64);
            if (lane == 0) ex[(t - half) >> 1] = __expf(sum);
          }
        }
        __syncthreads();
        const int n = (len - half + 1) >> 1;   // count of this block's t values
        // denominator partial
        if (tid < 64){
          float s2 = 0.f;
          for (int i = tid; i < n; i += 64) s2 += ex[i];
          #pragma unroll
          for (int off = 32; off > 0; off >>= 1) s2 += __shfl_xor(s2, off, 64);
          if (tid == 0 && n > 0) atomicAdd(&ws[OFF_DEN + p*32 + b], s2);
        }
        // scan this block's t set over hb16 (bf16, cached)
        {
          const int tg = tid >> 7;        // 0..3
          const int cl = tid & 127;
          const int col0 = cl*8;
          const unsigned short* hp = hb16 + (size_t)b*T_*ENC_ + col0;
          float acc[8] = {0.f,0.f,0.f,0.f,0.f,0.f,0.f,0.f};
          for (int idx = tg; idx < n; idx += 4){
            const int t = half + 2*idx;
            bf16x8 x = *(const bf16x8*)&hp[(size_t)t * ENC_];
            float a = ex[idx];
            #pragma unroll
            for (int j = 0; j < 8; ++j) acc[j] += a * bf2f((unsigned short)x[j]);
          }
          *(float4*)&pg[tg*1024 + col0]     = *(float4*)&acc[0];
          *(float4*)&pg[tg*1024 + col0 + 4] = *(float4*)&acc[4];
        }
        __syncthreads();
        if (tid < 256 && n > 0){
          const int c0 = tid*4;
          #pragma unroll
          for (int j = 0; j < 4; ++j){
            float s = pg[c0+j] + pg[1024+c0+j] + pg[2048+c0+j] + pg[3072+c0+j];
            atomicAdd(&ws[goff + b*ENC_ + c0 + j], s);
          }
        }
      }
    } else {
      if (l < L_){
        // zero next parity gU and den (hidden under the longer X phase)
        const int zoff = p ? OFF_G0 : OFF_G1;
        for (int i = (blk - 221)*NT_ + tid; i < B_*ENC_; i += 35*NT_)
          gstore(&ws[zoff + i], 0.f);
        if (blk == 221 && tid < 32)
          gstore(&ws[OFF_DEN + (p^1)*32 + tid], 0.f);
      }
    }
    if (l == L_) break;     // uniform exit
    gridbar(bars, (unsigned)(l*2 + 0));

    // ===== Y: [dect|racc] = [sP | gU/den] @ WrecHi (160 blocks, 1 vt) =====
    if (blk < 160){
      const float invb0 = 1.f / gload(&ws[OFF_DEN + p*32 + arow]);
      const float invb1 = 1.f / gload(&ws[OFF_DEN + p*32 + arow + 16]);
      const int vt = blk;
      f32x4 acc0 = {0.f,0.f,0.f,0.f}, acc1 = {0.f,0.f,0.f,0.f};
      for (int j6 = 0; j6 < 6; ++j6){
        const int kc = w*6 + j6;
        const int k0 = kc*32 + klane;
        const bool isg = (k0 >= 512);
        bf16x8 Ahi0, Alo0, Ahi1, Alo1;
        if (!isg){
          unsigned q[8];
          const unsigned* dp = sP + arow*H_ + k0;
          gloadu2(dp+0, q[0], q[1]);
          gloadu2(dp+2, q[2], q[3]);
          gloadu2(dp+4, q[4], q[5]);
          gloadu2(dp+6, q[6], q[7]);
          #pragma unroll
          for (int j = 0; j < 8; ++j){
            Ahi0[j] = (short)(q[j] >> 16);
            Alo0[j] = (short)(q[j] & 0xFFFFu);
          }
          const unsigned* dp1 = sP + (arow+16)*H_ + k0;
          gloadu2(dp1+0, q[0], q[1]);
          gloadu2(dp1+2, q[2], q[3]);
          gloadu2(dp1+4, q[4], q[5]);
          gloadu2(dp1+6, q[6], q[7]);
          #pragma unroll
          for (int j = 0; j < 8; ++j){
            Ahi1[j] = (short)(q[j] >> 16);
            Alo1[j] = (short)(q[j] & 0xFFFFu);
          }
        } else {
          {
            const float* src = &ws[goff + arow*ENC_ + (k0 - 512)];
            float x[8];
            gload2(src+0, x[0], x[1]);
            gload2(src+2, x[2], x[3]);
            gload2(src+4, x[4], x[5]);
            gload2(src+6, x[6], x[7]);
            #pragma unroll
            for (int j = 0; j < 8; ++j){
              short h, lo; bfsplit(x[j]*invb0, h, lo);
              Ahi0[j] = h; Alo0[j] = lo;
            }
          }
          {
            const float* src = &ws[goff + (arow+16)*ENC_ + (k0 - 512)];
            float x[8];
            gload2(src+0, x[0], x[1]);
            gload2(src+2, x[2], x[3]);
            gload2(src+4, x[4], x[5]);
            gload2(src+6, x[6], x[7]);
            #pragma unroll
            for (int j = 0; j < 8; ++j){
              short h, lo; bfsplit(x[j]*invb1, h, lo);
              Ahi1[j] = h; Alo1[j] = lo;
            }
          }
        }
        bf16x8 Bv = *(const bf16x8*)(wrecp + ((size_t)(vt*48 + kc)*64 + lane)*8);
        acc0 = mfma16(Ahi0, Bv, acc0);
        acc0 = mfma16(Alo0, Bv, acc0);
        acc1 = mfma16(Ahi1, Bv, acc1);
        acc1 = mfma16(Alo1, Bv, acc1);
      }
      // staged reduce across 8 k-waves: smem[w][rg][256]
      #pragma unroll
      for (int r = 0; r < 4; ++r){
        smem[(w*2 + 0)*256 + lane*4 + r] = acc0[r];
        smem[(w*2 + 1)*256 + lane*4 + r] = acc1[r];
      }
      __syncthreads();
      {
        const int bt = tid >> 8, r8 = tid & 255;
        float v = 0.f;
        #pragma unroll
        for (int w8 = 0; w8 < 8; ++w8)
          v += smem[(w8*2 + bt)*256 + r8];
        const int ln = r8 >> 2, rr = r8 & 3;
        const int row = bt*16 + ((ln >> 4) << 2) + rr;
        const int col = blk*16 + (ln & 15);
        if (col < 512){
          float t = ftanh(v + bsy[col] + bgy[col]);
          unsigned short hi_ = bfr(t);
          unsigned short lo_ = bfr(t - bf2f(hi_));
          gstoreu(&dectP[row*H_ + col], ((unsigned)hi_ << 16) | lo_);
        } else {
          gstore(&ws[OFF_RACC + row*H4_ + (col - 512)], v);
        }
      }
    }
    gridbar(bars, (unsigned)(l*2 + 1));
  }
}

extern "C" void kernel_launch(void* const* d_in, const int* in_sizes, int n_in,
                              void* d_out, int out_size, void* d_ws, size_t ws_size,
                              hipStream_t stream){
  const float* h_batch = (const float*)d_in[0];
  const int*   seq_lens= (const int*)d_in[1];
  const int*   labels  = (const int*)d_in[2];
  const float* attn_Ws = (const float*)d_in[3];
  const float* attn_Wh = (const float*)d_in[4];
  const float* attn_b  = (const float*)d_in[5];
  const float* attn_v  = (const float*)d_in[6];
  const float* W_sy    = (const float*)d_in[7];
  const float* b_sy    = (const float*)d_in[8];
  const float* W_gy    = (const float*)d_in[9];
  const float* b_gy    = (const float*)d_in[10];
  const float* W_yy    = (const float*)d_in[11];
  const float* b_yy    = (const float*)d_in[12];
  const float* E_yr    = (const float*)d_in[13];
  const float* W_sr    = (const float*)d_in[14];
  const float* b_sr    = (const float*)d_in[15];
  const float* W_gr    = (const float*)d_in[16];
  const float* b_gr    = (const float*)d_in[17];
  float* out = (float*)d_out;
  float* ws  = (float*)d_ws;

  k_init    <<<641, 256, 0, stream>>>(ws);
  k_packWyy <<<2500, 256, 0, stream>>>(W_yy, ws);
  k_packWrec<<<1920, 256, 0, stream>>>(W_sy, W_gy, W_sr, W_gr, ws);
  k_packWs  <<<1024, 256, 0, stream>>>(attn_Ws, ws);
  k_packHB  <<<64000, 256, 0, stream>>>(h_batch, ws);
  k_hproj   <<<dim3(250, 8), 256, 0, stream>>>(h_batch, attn_Wh, attn_b, seq_lens, ws);

  void* kargs[] = {
    (void*)&seq_lens, (void*)&labels, (void*)&attn_v,
    (void*)&b_sy, (void*)&b_gy, (void*)&b_yy,
    (void*)&E_yr, (void*)&b_sr, (void*)&b_gr,
    (void*)&out, (void*)&ws
  };
  hipLaunchCooperativeKernel((void*)k_persist, dim3(NB_), dim3(NT_), kargs, 0, stream);
}